// Round 1
// baseline (680.781 us; speedup 1.0000x reference)
//
#include <hip/hip_runtime.h>
#include <math.h>

#define T_STEPS 730
#define N_GRID  8000
#define NEARZERO 1e-5f

// Parameter bounds (LO/HI), folded to immediates in the unrolled loop.
__constant__ float c_lo[18] = {-3.f, 0.f, 0.f, 0.f, 0.f, 0.f, 0.f, 0.f, 0.005f, 1.f,    0.f, 1.f,   0.f, 1.f, 0.f, 0.f, 0.f, 0.f};
__constant__ float c_hi[18] = { 5.f, 20.f, 1.f, 1.f, 5.f, 50.f, 1.f, 1.f, 0.995f, 2000.f, 20.f, 300.f, 1.f, 5.f, 1.f, 1.f, 1.f, 1.f};

// One thread per grid cell; sequential over 730 timesteps.
// CH=10 chunked register prefetch: loads for chunk k+1 issued before compute
// of chunk k, keeping HBM latency (~900 cyc) hidden under ~10 steps of the
// dependent VALU chain. 730 = 73 * 10 exactly.
__global__ __launch_bounds__(64) void prms_kernel(
    const float* __restrict__ x,       // (T, N, 3)
    const float* __restrict__ params,  // (T, N, 18) -- only slab T-1 used
    float* __restrict__ out)           // (T, N)
{
    const int i = blockIdx.x * 64 + threadIdx.x;  // grid is exactly N_GRID/64 blocks

    // ---- one-time: sigmoid + rescale of the 18 parameters (last timestep) ----
    const float* pp = params + ((size_t)(T_STEPS - 1) * N_GRID + (size_t)i) * 18;
    float pr[18];
#pragma unroll
    for (int j = 0; j < 18; ++j) {
        float s = 1.0f / (1.0f + expf(-pp[j]));      // precise expf, once
        pr[j] = c_lo[j] + s * (c_hi[j] - c_lo[j]);
    }
    const float tt = pr[0],  ddf = pr[1],  alpha = pr[2], beta = pr[3];
    const float stor = pr[4], retip = pr[5], fscn = pr[6], scx = pr[7];
    const float flz = pr[8],  stot = pr[9],  cgw = pr[10], resmax = pr[11];
    const float k1 = pr[12],  k2 = pr[13],  k3 = pr[14],  k4 = pr[15];
    const float k5 = pr[16],  k6 = pr[17];

    const float scn       = fscn * scx;
    const float remx      = (1.0f - flz) * stot;
    const float smax      = flz * stot;
    const float inv_remx  = 1.0f / remx;
    const float inv_smax  = 1.0f / smax;
    const float inv_resmax = 1.0f / resmax;
    const float ombeta    = 1.0f - beta;
    const float omalpha   = 1.0f - alpha;

    // ---- state ----
    float snow = 0.001f, xin = 0.001f, rstor = 0.001f, rechr = 0.001f;
    float smav = 0.001f, res = 0.001f, gw = 0.001f;

    constexpr int CH = 10;
    float3 buf[CH];

    // preload chunk 0
#pragma unroll
    for (int u = 0; u < CH; ++u) {
        const float* q = x + ((size_t)u * N_GRID + (size_t)i) * 3;
        buf[u] = make_float3(q[0], q[1], q[2]);
    }

    for (int t0 = 0; t0 < T_STEPS; t0 += CH) {
        float3 nbuf[CH];
        const int tn = t0 + CH;
        if (tn < T_STEPS) {  // uniform branch
#pragma unroll
            for (int u = 0; u < CH; ++u) {
                const float* q = x + ((size_t)(tn + u) * N_GRID + (size_t)i) * 3;
                nbuf[u] = make_float3(q[0], q[1], q[2]);
            }
        }

#pragma unroll
        for (int u = 0; u < CH; ++u) {
            const float PRECIP = buf[u].x;
            const float temp   = buf[u].y;
            const float Ep     = buf[u].z;

            // snow partition + melt
            const bool snowy = (temp <= tt);
            const float flux_ps = snowy ? PRECIP : 0.0f;
            const float flux_pr = snowy ? 0.0f : PRECIP;
            snow = snow + flux_ps;
            float flux_m = fmaxf(ddf * (temp - tt), 0.0f);
            flux_m = fminf(flux_m, snow);
            snow = fmaxf(snow - flux_m, NEARZERO);

            // canopy interception
            const float flux_pim = flux_pr * ombeta;
            const float flux_psm = flux_pr * beta;
            const float flux_pby = flux_psm * omalpha;
            const float flux_pin = flux_psm * alpha;
            xin = xin + flux_pin;
            const float flux_ptf = fmaxf(xin - stor, 0.0f);
            xin = fmaxf(xin - flux_ptf, NEARZERO);
            const float flux_ein = fminf(Ep * beta, xin);
            xin = fmaxf(xin - flux_ein, NEARZERO);

            // impervious store
            const float flux_mim = flux_m * ombeta;
            const float flux_msm = flux_m * beta;
            rstor = rstor + flux_mim + flux_pim;
            const float flux_sas = fmaxf(rstor - retip, 0.0f);
            rstor = fmaxf(rstor - flux_sas, NEARZERO);
            const float flux_eim = fminf(ombeta * Ep, rstor);
            rstor = fmaxf(rstor - flux_eim, NEARZERO);

            // surface runoff (uses incoming rechr)
            float sro_lin = scn + (scx - scn) * (rechr * inv_remx);
            sro_lin = fminf(fmaxf(sro_lin, 0.0f), 1.0f);
            const float inflow  = flux_msm + flux_ptf + flux_pby;
            const float flux_sro = sro_lin * inflow;
            const float flux_inf = inflow - flux_sro;

            // recharge zone
            rechr = rechr + flux_inf;
            const float flux_pc = fmaxf(rechr - remx, 0.0f);
            rechr = rechr - flux_pc;
            const float ep_rem = Ep - flux_ein - flux_eim;
            const float evap_max_a = fmaxf(rechr * inv_remx * ep_rem, 0.0f);
            const float flux_ea = fminf(evap_max_a, rechr);
            rechr = fmaxf(rechr - flux_ea, NEARZERO);

            // soil moisture
            smav = smav + flux_pc;
            const float flux_excs = fmaxf(smav - smax, 0.0f);
            smav = smav - flux_excs;
            float transp = (rechr < ep_rem)
                         ? fmaxf(smav * inv_smax * (ep_rem - flux_ea), 0.0f)
                         : 0.0f;
            transp = fminf(transp, smav);
            smav = fmaxf(smav - transp, NEARZERO);

            // deep percolation / reservoir
            const float flux_sep  = fminf(cgw, flux_excs);
            const float flux_qres = fmaxf(flux_excs - flux_sep, 0.0f);
            res = res + flux_qres;
            // k1 * (res/resmax)^k2 via HW exp2/log2 (arg > 0 always; res >= NEARZERO)
            float flux_gad = k1 * __expf(k2 * __logf(res * inv_resmax));
            flux_gad = fminf(flux_gad, res);
            res = fmaxf(res - flux_gad, NEARZERO);
            float flux_ras = k3 * res + k4 * res * res;
            flux_ras = fminf(flux_ras, res);
            res = fmaxf(res - flux_ras, NEARZERO);

            // groundwater
            gw = gw + flux_gad + flux_sep;
            const float flux_bas = k5 * gw;
            gw = fmaxf(gw - flux_bas, NEARZERO);
            const float flux_snk = k6 * gw;
            gw = fmaxf(gw - flux_snk, NEARZERO);

            const float q = flux_sas + flux_sro + flux_bas + flux_ras;
            out[(size_t)(t0 + u) * N_GRID + (size_t)i] = q;
        }

#pragma unroll
        for (int u = 0; u < CH; ++u) buf[u] = nbuf[u];
    }
}

extern "C" void kernel_launch(void* const* d_in, const int* in_sizes, int n_in,
                              void* d_out, int out_size, void* d_ws, size_t ws_size,
                              hipStream_t stream) {
    const float* x      = (const float*)d_in[0];  // (730, 8000, 3)
    const float* params = (const float*)d_in[1];  // (730, 8000, 18)
    float* out          = (float*)d_out;          // (730, 8000)
    // 8000 / 64 = 125 blocks exactly -> one wave per CU on 125 CUs
    prms_kernel<<<dim3(N_GRID / 64), dim3(64), 0, stream>>>(x, params, out);
}

// Round 3
// 665.053 us; speedup vs baseline: 1.0236x; 1.0236x over previous
//
#include <hip/hip_runtime.h>
#include <math.h>

#define T_STEPS 730
#define N_GRID  8000
#define NEARZERO 1e-5f

__constant__ float c_lo[18] = {-3.f, 0.f, 0.f, 0.f, 0.f, 0.f, 0.f, 0.f, 0.005f, 1.f,    0.f, 1.f,   0.f, 1.f, 0.f, 0.f, 0.f, 0.f};
__constant__ float c_hi[18] = { 5.f, 20.f, 1.f, 1.f, 5.f, 50.f, 1.f, 1.f, 0.995f, 2000.f, 20.f, 300.f, 1.f, 5.f, 1.f, 1.f, 1.f, 1.f};

// HW transcendentals: v_exp_f32 computes 2^x, v_log_f32 computes log2(x).
#define EXP2F(v) __builtin_amdgcn_exp2f(v)
#define LOG2F(v) __builtin_amdgcn_logf(v)

// One thread per grid cell, sequential over 730 steps. Latency-bound:
// 125 lone waves (one per CU). Only lever = dependent-chain length.
// State updates use max(s - a, NZ) / max(min(s,c), NZ) collapsed forms so
// each state's self-cycle is minimal and fluxes branch OFF the cycle,
// enabling cross-step overlap by the scheduler over the unrolled chunk.
__global__ __launch_bounds__(64, 1) void prms_kernel(
    const float* __restrict__ x,       // (T, N, 3)
    const float* __restrict__ params,  // (T, N, 18) -- only slab T-1 used
    float* __restrict__ out)           // (T, N)
{
    const int i = blockIdx.x * 64 + threadIdx.x;

    const float* pp = params + ((size_t)(T_STEPS - 1) * N_GRID + (size_t)i) * 18;
    float pr[18];
#pragma unroll
    for (int j = 0; j < 18; ++j) {
        float s = 1.0f / (1.0f + expf(-pp[j]));      // precise, once
        pr[j] = c_lo[j] + s * (c_hi[j] - c_lo[j]);
    }
    const float tt = pr[0],  ddf = pr[1],  alpha = pr[2], beta = pr[3];
    const float stor = pr[4], retip = pr[5], fscn = pr[6], scx = pr[7];
    const float flz = pr[8],  stot = pr[9],  cgw = pr[10], resmax = pr[11];
    const float k1 = pr[12],  k2 = pr[13],  k3 = pr[14],  k4 = pr[15];
    const float k5 = pr[16],  k6 = pr[17];

    const float scn        = fscn * scx;
    const float remx       = (1.0f - flz) * stot;
    const float smax       = flz * stot;
    const float inv_remx   = 1.0f / remx;
    const float inv_smax   = 1.0f / smax;
    const float ombeta     = 1.0f - beta;
    const float omalpha    = 1.0f - alpha;
    const float omk5       = 1.0f - k5;
    const float omk6       = 1.0f - k6;
    const float dscn       = (scx - scn) * inv_remx;    // sro slope
    const float pow_c      = k2 * LOG2F(1.0f / resmax); // fold resmax into exp2 arg

    float snow = 0.001f, xin = 0.001f, rstor = 0.001f, rechr = 0.001f;
    float smav = 0.001f, res = 0.001f, gw = 0.001f;

    constexpr int CH = 10;                // 730 = 73 * 10
    float3 buf[CH];
#pragma unroll
    for (int u = 0; u < CH; ++u) {
        const float* q = x + ((size_t)u * N_GRID + (size_t)i) * 3;
        buf[u] = make_float3(q[0], q[1], q[2]);
    }

    for (int t0 = 0; t0 < T_STEPS; t0 += CH) {
        float3 nbuf[CH];
        const int tn = t0 + CH;
        if (tn < T_STEPS) {  // uniform
#pragma unroll
            for (int u = 0; u < CH; ++u) {
                const float* q = x + ((size_t)(tn + u) * N_GRID + (size_t)i) * 3;
                nbuf[u] = make_float3(q[0], q[1], q[2]);
            }
        }

#pragma unroll
        for (int u = 0; u < CH; ++u) {
            const float PRECIP = buf[u].x;
            const float temp   = buf[u].y;
            const float Ep     = buf[u].z;

            // ---- input-only precomputation (no state deps) ----
            const bool  snowy    = (temp <= tt);
            const float flux_ps  = snowy ? PRECIP : 0.0f;
            const float flux_pr  = snowy ? 0.0f : PRECIP;
            const float m0       = fmaxf(ddf * (temp - tt), 0.0f);   // melt cap
            const float flux_pim = flux_pr * ombeta;
            const float flux_psm = flux_pr * beta;
            const float flux_pby = flux_psm * omalpha;
            const float flux_pin = flux_psm * alpha;
            const float eb       = Ep * beta;          // >= 0
            const float eim_cap  = ombeta * Ep;        // >= 0

            // ---- snow (self-cycle: add, sub->max) ----
            const float snow1  = snow + flux_ps;
            const float flux_m = fminf(m0, snow1);
            snow = fmaxf(snow1 - m0, NEARZERO);        // == max(snow1 - flux_m, NZ)

            // ---- canopy xin ----
            const float xin1     = xin + flux_pin;
            const float flux_ptf = fmaxf(xin1 - stor, 0.0f);
            const float xin2     = fmaxf(fminf(xin1, stor), NEARZERO);
            const float flux_ein = fminf(eb, xin2);
            xin = fmaxf(xin2 - eb, NEARZERO);          // == max(xin2 - flux_ein, NZ)

            // ---- impervious rstor ----
            const float flux_mim = flux_m * ombeta;
            const float flux_msm = flux_m * beta;
            const float rstor1   = rstor + (flux_mim + flux_pim);
            const float flux_sas = fmaxf(rstor1 - retip, 0.0f);
            const float rstor2   = fmaxf(fminf(rstor1, retip), NEARZERO);
            const float flux_eim = fminf(eim_cap, rstor2);
            rstor = fmaxf(rstor2 - eim_cap, NEARZERO); // == max(rstor2 - flux_eim, NZ)

            // ---- surface runoff (uses incoming rechr) ----
            float sro_lin = scn + dscn * rechr;
            sro_lin = fminf(fmaxf(sro_lin, 0.0f), 1.0f);
            const float inflow   = flux_msm + (flux_ptf + flux_pby);
            const float flux_sro = sro_lin * inflow;
            const float flux_inf = inflow - flux_sro;

            // ---- recharge zone ----
            const float rechr1  = rechr + flux_inf;
            const float flux_pc = fmaxf(rechr1 - remx, 0.0f);
            const float rechr2  = fminf(rechr1, remx);            // > 0
            const float ep_rem  = Ep - flux_ein - flux_eim;
            const float emax    = fmaxf(rechr2 * inv_remx * ep_rem, 0.0f);
            const float flux_ea = fminf(emax, rechr2);
            rechr = fmaxf(rechr2 - emax, NEARZERO);    // == max(rechr2 - flux_ea, NZ)

            // ---- soil moisture ----
            const float smav1     = smav + flux_pc;
            const float flux_excs = fmaxf(smav1 - smax, 0.0f);
            const float smav2     = fminf(smav1, smax);           // >= NZ
            const float transp0   = fmaxf(smav2 * inv_smax * (ep_rem - flux_ea), 0.0f);
            const float tsub      = (rechr < ep_rem) ? transp0 : 0.0f;
            smav = fmaxf(smav2 - tsub, NEARZERO);

            // ---- reservoir ----
            const float flux_sep  = fminf(cgw, flux_excs);
            const float flux_qres = fmaxf(flux_excs - cgw, 0.0f); // == excs - min(cgw,excs)
            const float res1      = res + flux_qres;              // > 0
            const float gad0      = k1 * EXP2F(fmaf(k2, LOG2F(res1), pow_c));
            const float flux_gad  = fminf(gad0, res1);
            const float res2      = fmaxf(res1 - gad0, NEARZERO);
            const float ras0      = fmaf(k4, res2, k3) * res2;    // k3*r + k4*r^2
            const float flux_ras  = fminf(ras0, res2);
            res = fmaxf(res2 - ras0, NEARZERO);

            // ---- groundwater (5-op self-cycle) ----
            const float gw1      = gw + (flux_gad + flux_sep);
            const float flux_bas = k5 * gw1;
            const float gw2      = fmaxf(gw1 * omk5, NEARZERO);   // == max(gw1-bas, NZ)
            gw = fmaxf(gw2 * omk6, NEARZERO);

            const float q = (flux_sas + flux_sro) + (flux_bas + flux_ras);
            out[(size_t)(t0 + u) * N_GRID + (size_t)i] = q;
        }

#pragma unroll
        for (int u = 0; u < CH; ++u) buf[u] = nbuf[u];
    }
}

extern "C" void kernel_launch(void* const* d_in, const int* in_sizes, int n_in,
                              void* d_out, int out_size, void* d_ws, size_t ws_size,
                              hipStream_t stream) {
    const float* x      = (const float*)d_in[0];  // (730, 8000, 3)
    const float* params = (const float*)d_in[1];  // (730, 8000, 18)
    float* out          = (float*)d_out;          // (730, 8000)
    prms_kernel<<<dim3(N_GRID / 64), dim3(64), 0, stream>>>(x, params, out);
}